// Round 7
// baseline (845.424 us; speedup 1.0000x reference)
//
#include <hip/hip_runtime.h>

#define NN 20000
#define NE 320000
#define EPN (NE + NN)   // edges + self loops = 340000
#define RP_STRIDE 20004

// ---------------- CSR build ----------------
__global__ void k_init_counts(int* __restrict__ cnt) {
  int i = blockIdx.x * blockDim.x + threadIdx.x;
  if (i < 4 * NN) cnt[i] = 1;   // self loop
}

__global__ void k_count(const int* __restrict__ d0, const int* __restrict__ d1,
                        const int* __restrict__ d2, const int* __restrict__ d3,
                        int* __restrict__ cnt) {
  int i = blockIdx.x * blockDim.x + threadIdx.x;
  if (i >= 4 * NE) return;
  int t = i / NE, e = i - t * NE;
  const int* d = t == 0 ? d0 : t == 1 ? d1 : t == 2 ? d2 : d3;
  atomicAdd(&cnt[t * NN + d[e]], 1);
}

__global__ void k_scan(const int* __restrict__ cnt, int* __restrict__ rp, int* __restrict__ tmp) {
  int t = blockIdx.x;
  const int* c = cnt + t * NN;
  int* r = rp + t * RP_STRIDE;
  int* tm = tmp + t * NN;
  __shared__ int part[256];
  int tid = threadIdx.x;
  const int CH = (NN + 255) / 256;
  int lo = tid * CH, hi = min(lo + CH, NN);
  int s = 0;
  for (int i = lo; i < hi; i++) s += c[i];
  part[tid] = s;
  __syncthreads();
  if (tid == 0) {
    int run = 0;
    for (int i = 0; i < 256; i++) { int v = part[i]; part[i] = run; run += v; }
  }
  __syncthreads();
  int run = part[tid];
  for (int i = lo; i < hi; i++) { r[i] = run; tm[i] = run; run += c[i]; }
  if (lo < NN && hi == NN) r[NN] = run;
}

__global__ void k_fill(const int* __restrict__ e0, const int* __restrict__ e1,
                       const int* __restrict__ e2, const int* __restrict__ e3,
                       int* __restrict__ tmp, int* __restrict__ col) {
  int i = blockIdx.x * blockDim.x + threadIdx.x;
  if (i >= 4 * EPN) return;
  int t = i / EPN, j = i - t * EPN;
  const int* eb = t == 0 ? e0 : t == 1 ? e1 : t == 2 ? e2 : e3;
  int s, d;
  if (j < NE) { s = eb[j]; d = eb[NE + j]; } else { s = d = j - NE; }
  int pos = atomicAdd(&tmp[t * NN + d], 1);
  col[(size_t)t * EPN + pos] = s;
}

// ---------------- prep: PT[slot][k] = sum_c W[t][k][h*64+c]*a[t][h][c]; bmean ----
__global__ void k_prep(const float* __restrict__ W0, const float* __restrict__ as0,
                       const float* __restrict__ ad0, const float* __restrict__ b0,
                       const float* __restrict__ W1, const float* __restrict__ as1,
                       const float* __restrict__ ad1, const float* __restrict__ b1,
                       float* __restrict__ PT0, float* __restrict__ PT1,
                       float* __restrict__ bmean) {
  int i = blockIdx.x * blockDim.x + threadIdx.x;
  if (i < 4096) {          // PT0: r in [0,32), k in [0,128)
    int r = i >> 7, k = i & 127;
    int sd = r >> 4, t = (r >> 2) & 3, h = r & 3;
    const float* a = (sd ? ad0 : as0) + (t * 4 + h) * 64;
    const float* wr = W0 + ((size_t)t * 128 + k) * 256 + h * 64;
    float s = 0.f;
    for (int c = 0; c < 64; c++) s = fmaf(wr[c], a[c], s);
    PT0[r * 128 + k] = s;
  } else if (i < 6144) {   // PT1: r in [0,32), k in [0,64)
    int j = i - 4096;
    int r = j >> 6, k = j & 63;
    int sd = r >> 4, t = (r >> 2) & 3, h = r & 3;
    const float* a = (sd ? ad1 : as1) + (t * 4 + h) * 64;
    const float* wr = W1 + ((size_t)t * 64 + k) * 256 + h * 64;
    float s = 0.f;
    for (int c = 0; c < 64; c++) s = fmaf(wr[c], a[c], s);
    PT1[r * 64 + k] = s;
  } else if (i < 6272) {   // bmean[2][64]
    int j = i - 6144;
    int l = j >> 6, c = j & 63;
    const float* b = l ? b1 : b0;
    bmean[j] = 0.25f * (b[c] + b[64 + c] + b[128 + c] + b[192 + c]);
  }
}

// ---------------- coefficients: asrc/adst[v][16] = x[v] @ PT^T ----------------
template <int K>
__global__ __launch_bounds__(256) void k_coef(const float* __restrict__ xin,
                                              const float* __restrict__ PT,
                                              float* __restrict__ asrc,
                                              float* __restrict__ adst) {
  __shared__ float PTs[32][K + 4];
  __shared__ float Xs[4][K];
  int tid = threadIdx.x;
#pragma unroll
  for (int j = 0; j < (32 * K) / 1024; j++) {
    int f4 = tid + j * 256;
    int r = f4 / (K / 4), c4 = (f4 % (K / 4)) * 4;
    *(float4*)&PTs[r][c4] = *(const float4*)(PT + r * K + c4);
  }
  int w = tid >> 6, lane = tid & 63;
  int v = blockIdx.x * 4 + w;
  if (lane * 2 < K)
    *(float2*)&Xs[w][lane * 2] = *(const float2*)(xin + (size_t)v * K + lane * 2);
  __syncthreads();
  int s = lane & 31, h2 = lane >> 5;
  float acc = 0.f;
#pragma unroll
  for (int i = 0; i < K / 8; i++) {
    int k = h2 * (K / 2) + i * 4;
    float4 p = *(const float4*)&PTs[s][k];
    float4 xv = *(const float4*)&Xs[w][k];
    acc = fmaf(p.x, xv.x, fmaf(p.y, xv.y, fmaf(p.z, xv.z, fmaf(p.w, xv.w, acc))));
  }
  acc += __shfl_xor(acc, 32);
  if (lane < 16) asrc[(size_t)v * 16 + lane] = acc;
  else if (lane < 32) adst[(size_t)v * 16 + (lane - 16)] = acc;
}

// ---------------- x-space aggregation (per type): y[v][h][K] = sum alpha*x[src] --
// wave = 1 dst; G edge-groups of K/4 lanes; online softmax from asrc gathers only.
template <int K>
__global__ __launch_bounds__(256) void k_aggx(
    const int* __restrict__ rp, const int* __restrict__ col,
    const float* __restrict__ asrc, const float* __restrict__ adst,  // +t*4 offset
    const float* __restrict__ x, float* __restrict__ y) {
  constexpr int G = 256 / K;   // 2 (K=128) or 4 (K=64)
  constexpr int GL = K / 4;    // lanes per group
  int v = blockIdx.x * 4 + (threadIdx.x >> 6);
  int lane = threadIdx.x & 63;
  int g = lane / GL;
  int c4 = (lane % GL) * 4;
  int beg = rp[v], deg = rp[v + 1] - beg;
  float4 advec = *(const float4*)(adst + (size_t)v * 16);
  float adv[4] = {advec.x, advec.y, advec.z, advec.w};

  // pass 1: online (m,z) per head
  float m[4] = {-1e30f, -1e30f, -1e30f, -1e30f};
  float z[4] = {0.f, 0.f, 0.f, 0.f};
  for (int i = g; i < deg; i += G) {
    int s = col[beg + i];
    float4 a = *(const float4*)(asrc + (size_t)s * 16);
    float av[4] = {a.x, a.y, a.z, a.w};
#pragma unroll
    for (int h = 0; h < 4; h++) {
      float e = av[h] + adv[h];
      e = e > 0.f ? e : 0.2f * e;
      float nm = fmaxf(m[h], e);
      z[h] = z[h] * __expf(m[h] - nm) + __expf(e - nm);
      m[h] = nm;
    }
  }
#pragma unroll
  for (int st = GL; st < 64; st <<= 1) {
#pragma unroll
    for (int h = 0; h < 4; h++) {
      float m2 = __shfl_xor(m[h], st);
      float z2 = __shfl_xor(z[h], st);
      float nm = fmaxf(m[h], m2);
      z[h] = z[h] * __expf(m[h] - nm) + z2 * __expf(m2 - nm);
      m[h] = nm;
    }
  }
  float rz[4];
#pragma unroll
  for (int h = 0; h < 4; h++) rz[h] = 1.f / z[h];

  // pass 2: weighted x gather
  float acc[4][4] = {};
  for (int i = g; i < deg; i += G) {
    int s = col[beg + i];
    float4 a = *(const float4*)(asrc + (size_t)s * 16);
    float4 xv = *(const float4*)(x + (size_t)s * K + c4);
    float av[4] = {a.x, a.y, a.z, a.w};
#pragma unroll
    for (int h = 0; h < 4; h++) {
      float e = av[h] + adv[h];
      e = e > 0.f ? e : 0.2f * e;
      float w = __expf(e - m[h]);
      acc[h][0] = fmaf(w, xv.x, acc[h][0]);
      acc[h][1] = fmaf(w, xv.y, acc[h][1]);
      acc[h][2] = fmaf(w, xv.z, acc[h][2]);
      acc[h][3] = fmaf(w, xv.w, acc[h][3]);
    }
  }
#pragma unroll
  for (int st = GL; st < 64; st <<= 1)
#pragma unroll
    for (int h = 0; h < 4; h++) {
      acc[h][0] += __shfl_xor(acc[h][0], st);
      acc[h][1] += __shfl_xor(acc[h][1], st);
      acc[h][2] += __shfl_xor(acc[h][2], st);
      acc[h][3] += __shfl_xor(acc[h][3], st);
    }
  if (lane < GL) {
#pragma unroll
    for (int h = 0; h < 4; h++)
      *(float4*)(y + (size_t)v * (4 * K) + h * K + c4) =
          make_float4(acc[h][0] * rz[h], acc[h][1] * rz[h],
                      acc[h][2] * rz[h], acc[h][3] * rz[h]);
  }
}

// ---------------- per-type output GEMM: z_t = y @ B_t (B read from W) ----------
template <int K>
__global__ __launch_bounds__(256) void k_out(const float* __restrict__ y,
                                             const float* __restrict__ Wt,
                                             float* __restrict__ z) {
  constexpr int KT = 4 * K;
  __shared__ float As[32][68];
  __shared__ float Bs[32][68];
  int tid = threadIdx.x;
  int row0 = blockIdx.x * 64;
  int tx = tid & 15, ty = tid >> 4;
  float acc[4][4] = {};
  for (int kb = 0; kb < KT; kb += 32) {
    int h = kb / K;
    int kk0 = kb % K;
#pragma unroll
    for (int j = 0; j < 2; j++) {
      int idx = tid + j * 256;
      int r = idx >> 3, k4 = (idx & 7) * 4;
      float4 vv = make_float4(0.f, 0.f, 0.f, 0.f);
      if (row0 + r < NN) vv = *(const float4*)(y + (size_t)(row0 + r) * KT + kb + k4);
      As[k4 + 0][r] = vv.x; As[k4 + 1][r] = vv.y;
      As[k4 + 2][r] = vv.z; As[k4 + 3][r] = vv.w;
    }
#pragma unroll
    for (int j = 0; j < 2; j++) {
      int idx = tid + j * 256;
      int kk = idx >> 4, cc4 = (idx & 15) * 4;
      *(float4*)&Bs[kk][cc4] =
          *(const float4*)(Wt + (size_t)(kk0 + kk) * 256 + h * 64 + cc4);
    }
    __syncthreads();
#pragma unroll 4
    for (int kk = 0; kk < 32; kk++) {
      float4 a4 = *(const float4*)&As[kk][ty * 4];
      float4 b4 = *(const float4*)&Bs[kk][tx * 4];
      float aa[4] = {a4.x, a4.y, a4.z, a4.w};
      float bb[4] = {b4.x, b4.y, b4.z, b4.w};
#pragma unroll
      for (int i = 0; i < 4; i++)
#pragma unroll
        for (int j = 0; j < 4; j++) acc[i][j] = fmaf(aa[i], bb[j], acc[i][j]);
    }
    __syncthreads();
  }
#pragma unroll
  for (int i = 0; i < 4; i++) {
    int gr = row0 + ty * 4 + i;
    if (gr < NN)
      *(float4*)(z + (size_t)gr * 64 + tx * 4) =
          make_float4(acc[i][0], acc[i][1], acc[i][2], acc[i][3]);
  }
}

// ---------------- finalize: relu((1/16)*sum_t z_t + bmean) ----------------
// z_t is the head-SUM for type t; 1/16 = head-mean (1/4) x type-mean (1/4).
__global__ void k_fin(const float* __restrict__ z, const float* __restrict__ bm,
                      float* __restrict__ xout) {
  int i = blockIdx.x * blockDim.x + threadIdx.x;
  if (i < NN * 64) {
    float s = z[i] + z[i + NN * 64] + z[i + 2 * NN * 64] + z[i + 3 * NN * 64];
    xout[i] = fmaxf(0.0625f * s + bm[i & 63], 0.f);
  }
}

__global__ void k_linear(const float* __restrict__ x, const float* __restrict__ W,
                         const float* __restrict__ b, float* __restrict__ out) {
  int i = blockIdx.x * blockDim.x + threadIdx.x;
  if (i >= NN * 32) return;
  int v = i >> 5, o = i & 31;
  float acc = b[o];
#pragma unroll
  for (int c = 0; c < 64; c++) acc = fmaf(x[v * 64 + c], W[c * 32 + o], acc);
  out[i] = acc;
}

extern "C" void kernel_launch(void* const* d_in, const int* in_sizes, int n_in,
                              void* d_out, int out_size, void* d_ws, size_t ws_size,
                              hipStream_t stream) {
  const float* x = (const float*)d_in[0];
  const int* e0 = (const int*)d_in[1];
  const int* e1 = (const int*)d_in[2];
  const int* e2 = (const int*)d_in[3];
  const int* e3 = (const int*)d_in[4];
  const float* W0 = (const float*)d_in[5];
  const float* as0 = (const float*)d_in[6];
  const float* ad0 = (const float*)d_in[7];
  const float* b0 = (const float*)d_in[8];
  const float* W1 = (const float*)d_in[9];
  const float* as1 = (const float*)d_in[10];
  const float* ad1 = (const float*)d_in[11];
  const float* b1 = (const float*)d_in[12];
  const float* linW = (const float*)d_in[13];
  const float* linb = (const float*)d_in[14];
  float* out = (float*)d_out;
  (void)in_sizes; (void)n_in; (void)out_size; (void)ws_size;

  char* wsb = (char*)d_ws;
  size_t off = 0;
  auto carve = [&](size_t bytes) -> char* {
    off = (off + 255) & ~(size_t)255;
    char* p = wsb + off;
    off += bytes;
    return p;
  };
  int* cnt     = (int*)carve((size_t)4 * NN * sizeof(int));
  int* tmp     = (int*)carve((size_t)4 * NN * sizeof(int));
  int* rp      = (int*)carve((size_t)4 * RP_STRIDE * sizeof(int));
  int* col     = (int*)carve((size_t)4 * EPN * sizeof(int));
  float* asrc  = (float*)carve((size_t)NN * 16 * sizeof(float));
  float* adst  = (float*)carve((size_t)NN * 16 * sizeof(float));
  float* PT0   = (float*)carve((size_t)32 * 128 * sizeof(float));
  float* PT1   = (float*)carve((size_t)32 * 64 * sizeof(float));
  float* bmean = (float*)carve((size_t)128 * sizeof(float));
  float* y     = (float*)carve((size_t)NN * 512 * sizeof(float));
  float* zsep  = (float*)carve((size_t)4 * NN * 64 * sizeof(float));
  float* xmid  = (float*)carve((size_t)NN * 64 * sizeof(float));

  // CSR build (edges identical across layers -> build once per call)
  k_init_counts<<<(4 * NN + 255) / 256, 256, 0, stream>>>(cnt);
  k_count<<<(4 * NE + 255) / 256, 256, 0, stream>>>(e0 + NE, e1 + NE, e2 + NE, e3 + NE, cnt);
  k_scan<<<4, 256, 0, stream>>>(cnt, rp, tmp);
  k_fill<<<(4 * EPN + 255) / 256, 256, 0, stream>>>(e0, e1, e2, e3, tmp, col);

  k_prep<<<25, 256, 0, stream>>>(W0, as0, ad0, b0, W1, as1, ad1, b1, PT0, PT1, bmean);

  // ---- layer 0 (K=128) ----
  k_coef<128><<<5000, 256, 0, stream>>>(x, PT0, asrc, adst);
  for (int t = 0; t < 4; t++) {
    k_aggx<128><<<5000, 256, 0, stream>>>(rp + t * RP_STRIDE, col + (size_t)t * EPN,
                                          asrc + t * 4, adst + t * 4, x, y);
    k_out<128><<<313, 256, 0, stream>>>(y, W0 + (size_t)t * 128 * 256,
                                        zsep + (size_t)t * NN * 64);
  }
  k_fin<<<(NN * 64 + 255) / 256, 256, 0, stream>>>(zsep, bmean, xmid);

  // ---- layer 1 (K=64) ----
  k_coef<64><<<5000, 256, 0, stream>>>(xmid, PT1, asrc, adst);
  for (int t = 0; t < 4; t++) {
    k_aggx<64><<<5000, 256, 0, stream>>>(rp + t * RP_STRIDE, col + (size_t)t * EPN,
                                         asrc + t * 4, adst + t * 4, xmid, y);
    k_out<64><<<313, 256, 0, stream>>>(y, W1 + (size_t)t * 64 * 256,
                                       zsep + (size_t)t * NN * 64);
  }
  k_fin<<<(NN * 64 + 255) / 256, 256, 0, stream>>>(zsep, bmean + 64, xmid);

  k_linear<<<(NN * 32 + 255) / 256, 256, 0, stream>>>(xmid, linW, linb, out);
}

// Round 8
// 682.490 us; speedup vs baseline: 1.2387x; 1.2387x over previous
//
#include <hip/hip_runtime.h>

#define NN 20000
#define NE 320000
#define EPN (NE + NN)   // edges + self loops = 340000
#define RP_STRIDE 20004
#define DCAP 96

// ---------------- CSR build ----------------
__global__ void k_count(const int* __restrict__ d0, const int* __restrict__ d1,
                        const int* __restrict__ d2, const int* __restrict__ d3,
                        int* __restrict__ cnt) {
  int i = blockIdx.x * blockDim.x + threadIdx.x;
  if (i >= 4 * NE) return;
  int t = i / NE, e = i - t * NE;
  const int* d = t == 0 ? d0 : t == 1 ? d1 : t == 2 ? d2 : d3;
  atomicAdd(&cnt[t * NN + d[e]], 1);
}

// self-loop (+1 per node) folded into the scan
__global__ void k_scan(const int* __restrict__ cnt, int* __restrict__ rp, int* __restrict__ tmp) {
  int t = blockIdx.x;
  const int* c = cnt + t * NN;
  int* r = rp + t * RP_STRIDE;
  int* tm = tmp + t * NN;
  __shared__ int part[256];
  int tid = threadIdx.x;
  const int CH = (NN + 255) / 256;
  int lo = tid * CH, hi = min(lo + CH, NN);
  int s = 0;
  for (int i = lo; i < hi; i++) s += c[i] + 1;
  part[tid] = s;
  __syncthreads();
  if (tid == 0) {
    int run = 0;
    for (int i = 0; i < 256; i++) { int v = part[i]; part[i] = run; run += v; }
  }
  __syncthreads();
  int run = part[tid];
  for (int i = lo; i < hi; i++) { r[i] = run; tm[i] = run; run += c[i] + 1; }
  if (lo < NN && hi == NN) r[NN] = run;
}

__global__ void k_fill(const int* __restrict__ e0, const int* __restrict__ e1,
                       const int* __restrict__ e2, const int* __restrict__ e3,
                       int* __restrict__ tmp, int* __restrict__ col) {
  int i = blockIdx.x * blockDim.x + threadIdx.x;
  if (i >= 4 * EPN) return;
  int t = i / EPN, j = i - t * EPN;
  const int* eb = t == 0 ? e0 : t == 1 ? e1 : t == 2 ? e2 : e3;
  int s, d;
  if (j < NE) { s = eb[j]; d = eb[NE + j]; } else { s = d = j - NE; }
  int pos = atomicAdd(&tmp[t * NN + d], 1);
  col[(size_t)t * EPN + pos] = s;
}

// ---------------- prep: PT[slot][k] = sum_c W[t][k][h*64+c]*a[t][h][c]; bmean ----
__global__ void k_prep(const float* __restrict__ W0, const float* __restrict__ as0,
                       const float* __restrict__ ad0, const float* __restrict__ b0,
                       const float* __restrict__ W1, const float* __restrict__ as1,
                       const float* __restrict__ ad1, const float* __restrict__ b1,
                       float* __restrict__ PT0, float* __restrict__ PT1,
                       float* __restrict__ bmean) {
  int i = blockIdx.x * blockDim.x + threadIdx.x;
  if (i < 4096) {
    int r = i >> 7, k = i & 127;
    int sd = r >> 4, t = (r >> 2) & 3, h = r & 3;
    const float* a = (sd ? ad0 : as0) + (t * 4 + h) * 64;
    const float* wr = W0 + ((size_t)t * 128 + k) * 256 + h * 64;
    float s = 0.f;
    for (int c = 0; c < 64; c++) s = fmaf(wr[c], a[c], s);
    PT0[r * 128 + k] = s;
  } else if (i < 6144) {
    int j = i - 4096;
    int r = j >> 6, k = j & 63;
    int sd = r >> 4, t = (r >> 2) & 3, h = r & 3;
    const float* a = (sd ? ad1 : as1) + (t * 4 + h) * 64;
    const float* wr = W1 + ((size_t)t * 64 + k) * 256 + h * 64;
    float s = 0.f;
    for (int c = 0; c < 64; c++) s = fmaf(wr[c], a[c], s);
    PT1[r * 64 + k] = s;
  } else if (i < 6272) {
    int j = i - 6144;
    int l = j >> 6, c = j & 63;
    const float* b = l ? b1 : b0;
    bmean[j] = 0.25f * (b[c] + b[64 + c] + b[128 + c] + b[192 + c]);
  }
}

// ---------------- coefficients: asrc/adst[v][16] = x[v] @ PT^T ----------------
template <int K>
__global__ __launch_bounds__(256) void k_coef(const float* __restrict__ xin,
                                              const float* __restrict__ PT,
                                              float* __restrict__ asrc,
                                              float* __restrict__ adst) {
  __shared__ float PTs[32][K + 4];
  __shared__ float Xs[4][K];
  int tid = threadIdx.x;
#pragma unroll
  for (int j = 0; j < (32 * K) / 1024; j++) {
    int f4 = tid + j * 256;
    int r = f4 / (K / 4), c4 = (f4 % (K / 4)) * 4;
    *(float4*)&PTs[r][c4] = *(const float4*)(PT + r * K + c4);
  }
  int w = tid >> 6, lane = tid & 63;
  int v = blockIdx.x * 4 + w;
  if (lane * 2 < K)
    *(float2*)&Xs[w][lane * 2] = *(const float2*)(xin + (size_t)v * K + lane * 2);
  __syncthreads();
  int s = lane & 31, h2 = lane >> 5;
  float acc = 0.f;
#pragma unroll
  for (int i = 0; i < K / 8; i++) {
    int k = h2 * (K / 2) + i * 4;
    float4 p = *(const float4*)&PTs[s][k];
    float4 xv = *(const float4*)&Xs[w][k];
    acc = fmaf(p.x, xv.x, fmaf(p.y, xv.y, fmaf(p.z, xv.z, fmaf(p.w, xv.w, acc))));
  }
  acc += __shfl_xor(acc, 32);
  if (lane < 16) asrc[(size_t)v * 16 + lane] = acc;
  else if (lane < 32) adst[(size_t)v * 16 + (lane - 16)] = acc;
}

// ---------------- x-space aggregation v2: wave = 1 (node,type) --------------
// Pass1: edge-per-lane (64-wide), asrc gathered ONCE, e->LDS, plain fmax tree.
// Exp pass LDS-local. Pass2: pure gather (LDS w broadcast + coalesced x row).
template <int K>
__global__ __launch_bounds__(256) void k_aggx2(
    const int* __restrict__ rp, const int* __restrict__ col,
    const float* __restrict__ asrc, const float* __restrict__ adst,  // +t*4 pre-offset
    const float* __restrict__ x, float* __restrict__ y, int ystride) {
  constexpr int GL = K / 4;    // lanes per group (32 / 16)
  constexpr int G = 64 / GL;   // edge groups per wave (2 / 4)
  __shared__ float wl[4][DCAP * 4];
  __shared__ int scol[4][DCAP];
  int w = threadIdx.x >> 6, lane = threadIdx.x & 63;
  int v = blockIdx.x * 4 + w;
  int beg = rp[v], deg = rp[v + 1] - beg;
  float4 adv = *(const float4*)(adst + (size_t)v * 16);
  int g = lane / GL, c4 = (lane % GL) * 4;
  float acc[4][4] = {};
  float rz[4];

  if (deg <= DCAP) {
    float m0 = -1e30f, m1 = -1e30f, m2 = -1e30f, m3 = -1e30f;
    for (int i = lane; i < deg; i += 64) {
      int s = col[beg + i];
      scol[w][i] = s;
      float4 a = *(const float4*)(asrc + (size_t)s * 16);
      float e0 = a.x + adv.x; e0 = e0 > 0.f ? e0 : 0.2f * e0;
      float e1 = a.y + adv.y; e1 = e1 > 0.f ? e1 : 0.2f * e1;
      float e2 = a.z + adv.z; e2 = e2 > 0.f ? e2 : 0.2f * e2;
      float e3 = a.w + adv.w; e3 = e3 > 0.f ? e3 : 0.2f * e3;
      *(float4*)&wl[w][i * 4] = make_float4(e0, e1, e2, e3);
      m0 = fmaxf(m0, e0); m1 = fmaxf(m1, e1);
      m2 = fmaxf(m2, e2); m3 = fmaxf(m3, e3);
    }
#pragma unroll
    for (int st = 1; st < 64; st <<= 1) {
      m0 = fmaxf(m0, __shfl_xor(m0, st)); m1 = fmaxf(m1, __shfl_xor(m1, st));
      m2 = fmaxf(m2, __shfl_xor(m2, st)); m3 = fmaxf(m3, __shfl_xor(m3, st));
    }
    float z0 = 0.f, z1 = 0.f, z2 = 0.f, z3 = 0.f;
    for (int i = lane; i < deg; i += 64) {
      float4 e = *(const float4*)&wl[w][i * 4];
      e.x = __expf(e.x - m0); e.y = __expf(e.y - m1);
      e.z = __expf(e.z - m2); e.w = __expf(e.w - m3);
      *(float4*)&wl[w][i * 4] = e;
      z0 += e.x; z1 += e.y; z2 += e.z; z3 += e.w;
    }
#pragma unroll
    for (int st = 1; st < 64; st <<= 1) {
      z0 += __shfl_xor(z0, st); z1 += __shfl_xor(z1, st);
      z2 += __shfl_xor(z2, st); z3 += __shfl_xor(z3, st);
    }
    rz[0] = 1.f / z0; rz[1] = 1.f / z1; rz[2] = 1.f / z2; rz[3] = 1.f / z3;
    // pass 2: pure gather (wave-synchronous LDS, no barrier needed)
    for (int i = g; i < deg; i += G) {
      float4 wv = *(const float4*)&wl[w][i * 4];
      float4 xv = *(const float4*)(x + (size_t)scol[w][i] * K + c4);
      acc[0][0] = fmaf(wv.x, xv.x, acc[0][0]); acc[0][1] = fmaf(wv.x, xv.y, acc[0][1]);
      acc[0][2] = fmaf(wv.x, xv.z, acc[0][2]); acc[0][3] = fmaf(wv.x, xv.w, acc[0][3]);
      acc[1][0] = fmaf(wv.y, xv.x, acc[1][0]); acc[1][1] = fmaf(wv.y, xv.y, acc[1][1]);
      acc[1][2] = fmaf(wv.y, xv.z, acc[1][2]); acc[1][3] = fmaf(wv.y, xv.w, acc[1][3]);
      acc[2][0] = fmaf(wv.z, xv.x, acc[2][0]); acc[2][1] = fmaf(wv.z, xv.y, acc[2][1]);
      acc[2][2] = fmaf(wv.z, xv.z, acc[2][2]); acc[2][3] = fmaf(wv.z, xv.w, acc[2][3]);
      acc[3][0] = fmaf(wv.w, xv.x, acc[3][0]); acc[3][1] = fmaf(wv.w, xv.y, acc[3][1]);
      acc[3][2] = fmaf(wv.w, xv.z, acc[3][2]); acc[3][3] = fmaf(wv.w, xv.w, acc[3][3]);
    }
  } else {
    // fallback: online softmax (deg unbounded)
    float m[4] = {-1e30f, -1e30f, -1e30f, -1e30f};
    float z[4] = {0.f, 0.f, 0.f, 0.f};
    float advv[4] = {adv.x, adv.y, adv.z, adv.w};
    for (int i = g; i < deg; i += G) {
      int s = col[beg + i];
      float4 a = *(const float4*)(asrc + (size_t)s * 16);
      float av[4] = {a.x, a.y, a.z, a.w};
#pragma unroll
      for (int h = 0; h < 4; h++) {
        float e = av[h] + advv[h];
        e = e > 0.f ? e : 0.2f * e;
        float nm = fmaxf(m[h], e);
        z[h] = z[h] * __expf(m[h] - nm) + __expf(e - nm);
        m[h] = nm;
      }
    }
#pragma unroll
    for (int st = GL; st < 64; st <<= 1)
#pragma unroll
      for (int h = 0; h < 4; h++) {
        float m2_ = __shfl_xor(m[h], st);
        float z2_ = __shfl_xor(z[h], st);
        float nm = fmaxf(m[h], m2_);
        z[h] = z[h] * __expf(m[h] - nm) + z2_ * __expf(m2_ - nm);
        m[h] = nm;
      }
#pragma unroll
    for (int h = 0; h < 4; h++) rz[h] = 1.f / z[h];
    for (int i = g; i < deg; i += G) {
      int s = col[beg + i];
      float4 a = *(const float4*)(asrc + (size_t)s * 16);
      float4 xv = *(const float4*)(x + (size_t)s * K + c4);
      float av[4] = {a.x, a.y, a.z, a.w};
#pragma unroll
      for (int h = 0; h < 4; h++) {
        float e = av[h] + advv[h];
        e = e > 0.f ? e : 0.2f * e;
        float ww = __expf(e - m[h]);
        acc[h][0] = fmaf(ww, xv.x, acc[h][0]);
        acc[h][1] = fmaf(ww, xv.y, acc[h][1]);
        acc[h][2] = fmaf(ww, xv.z, acc[h][2]);
        acc[h][3] = fmaf(ww, xv.w, acc[h][3]);
      }
    }
  }
#pragma unroll
  for (int st = GL; st < 64; st <<= 1)
#pragma unroll
    for (int h = 0; h < 4; h++) {
      acc[h][0] += __shfl_xor(acc[h][0], st);
      acc[h][1] += __shfl_xor(acc[h][1], st);
      acc[h][2] += __shfl_xor(acc[h][2], st);
      acc[h][3] += __shfl_xor(acc[h][3], st);
    }
  if (lane < GL) {
#pragma unroll
    for (int h = 0; h < 4; h++)
      *(float4*)(y + (size_t)v * ystride + h * K + c4) =
          make_float4(acc[h][0] * rz[h], acc[h][1] * rz[h],
                      acc[h][2] * rz[h], acc[h][3] * rz[h]);
  }
}

// ------- merged output GEMM: xout = relu(1/16 * y[NN][16K] @ B + bmean) -------
template <int K>
__global__ __launch_bounds__(256) void k_out_m(const float* __restrict__ y,
                                               const float* __restrict__ W,
                                               const float* __restrict__ bm,
                                               float* __restrict__ xout) {
  constexpr int KT = 16 * K;
  __shared__ float As[32][68];
  __shared__ float Bs[32][68];
  int tid = threadIdx.x;
  int row0 = blockIdx.x * 64;
  int tx = tid & 15, ty = tid >> 4;
  float acc[4][4] = {};
  for (int kb = 0; kb < KT; kb += 32) {
    int tt = kb / (4 * K), hh = (kb / K) & 3, kk0 = kb % K;
#pragma unroll
    for (int j = 0; j < 2; j++) {
      int idx = tid + j * 256;
      int r = idx >> 3, k4 = (idx & 7) * 4;
      float4 vv = make_float4(0.f, 0.f, 0.f, 0.f);
      if (row0 + r < NN) vv = *(const float4*)(y + (size_t)(row0 + r) * KT + kb + k4);
      As[k4 + 0][r] = vv.x; As[k4 + 1][r] = vv.y;
      As[k4 + 2][r] = vv.z; As[k4 + 3][r] = vv.w;
    }
#pragma unroll
    for (int j = 0; j < 2; j++) {
      int idx = tid + j * 256;
      int kk = idx >> 4, cc4 = (idx & 15) * 4;
      *(float4*)&Bs[kk][cc4] =
          *(const float4*)(W + ((size_t)tt * K + kk0 + kk) * 256 + hh * 64 + cc4);
    }
    __syncthreads();
#pragma unroll 4
    for (int kk = 0; kk < 32; kk++) {
      float4 a4 = *(const float4*)&As[kk][ty * 4];
      float4 b4 = *(const float4*)&Bs[kk][tx * 4];
      float aa[4] = {a4.x, a4.y, a4.z, a4.w};
      float bb[4] = {b4.x, b4.y, b4.z, b4.w};
#pragma unroll
      for (int i = 0; i < 4; i++)
#pragma unroll
        for (int j = 0; j < 4; j++) acc[i][j] = fmaf(aa[i], bb[j], acc[i][j]);
    }
    __syncthreads();
  }
#pragma unroll
  for (int i = 0; i < 4; i++) {
    int gr = row0 + ty * 4 + i;
    if (gr < NN) {
      float4 o;
      o.x = fmaxf(0.0625f * acc[i][0] + bm[tx * 4 + 0], 0.f);
      o.y = fmaxf(0.0625f * acc[i][1] + bm[tx * 4 + 1], 0.f);
      o.z = fmaxf(0.0625f * acc[i][2] + bm[tx * 4 + 2], 0.f);
      o.w = fmaxf(0.0625f * acc[i][3] + bm[tx * 4 + 3], 0.f);
      *(float4*)(xout + (size_t)gr * 64 + tx * 4) = o;
    }
  }
}

// ---------------- fallback path (small ws): per-type out + fin ----------------
template <int K>
__global__ __launch_bounds__(256) void k_out(const float* __restrict__ y,
                                             const float* __restrict__ Wt,
                                             float* __restrict__ z) {
  constexpr int KT = 4 * K;
  __shared__ float As[32][68];
  __shared__ float Bs[32][68];
  int tid = threadIdx.x;
  int row0 = blockIdx.x * 64;
  int tx = tid & 15, ty = tid >> 4;
  float acc[4][4] = {};
  for (int kb = 0; kb < KT; kb += 32) {
    int h = kb / K, kk0 = kb % K;
#pragma unroll
    for (int j = 0; j < 2; j++) {
      int idx = tid + j * 256;
      int r = idx >> 3, k4 = (idx & 7) * 4;
      float4 vv = make_float4(0.f, 0.f, 0.f, 0.f);
      if (row0 + r < NN) vv = *(const float4*)(y + (size_t)(row0 + r) * KT + kb + k4);
      As[k4 + 0][r] = vv.x; As[k4 + 1][r] = vv.y;
      As[k4 + 2][r] = vv.z; As[k4 + 3][r] = vv.w;
    }
#pragma unroll
    for (int j = 0; j < 2; j++) {
      int idx = tid + j * 256;
      int kk = idx >> 4, cc4 = (idx & 15) * 4;
      *(float4*)&Bs[kk][cc4] =
          *(const float4*)(Wt + (size_t)(kk0 + kk) * 256 + h * 64 + cc4);
    }
    __syncthreads();
#pragma unroll 4
    for (int kk = 0; kk < 32; kk++) {
      float4 a4 = *(const float4*)&As[kk][ty * 4];
      float4 b4 = *(const float4*)&Bs[kk][tx * 4];
      float aa[4] = {a4.x, a4.y, a4.z, a4.w};
      float bb[4] = {b4.x, b4.y, b4.z, b4.w};
#pragma unroll
      for (int i = 0; i < 4; i++)
#pragma unroll
        for (int j = 0; j < 4; j++) acc[i][j] = fmaf(aa[i], bb[j], acc[i][j]);
    }
    __syncthreads();
  }
#pragma unroll
  for (int i = 0; i < 4; i++) {
    int gr = row0 + ty * 4 + i;
    if (gr < NN)
      *(float4*)(z + (size_t)gr * 64 + tx * 4) =
          make_float4(acc[i][0], acc[i][1], acc[i][2], acc[i][3]);
  }
}

__global__ void k_fin(const float* __restrict__ z, const float* __restrict__ bm,
                      float* __restrict__ xout) {
  int i = blockIdx.x * blockDim.x + threadIdx.x;
  if (i < NN * 64) {
    float s = z[i] + z[i + NN * 64] + z[i + 2 * NN * 64] + z[i + 3 * NN * 64];
    xout[i] = fmaxf(0.0625f * s + bm[i & 63], 0.f);
  }
}

__global__ void k_linear(const float* __restrict__ x, const float* __restrict__ W,
                         const float* __restrict__ b, float* __restrict__ out) {
  int i = blockIdx.x * blockDim.x + threadIdx.x;
  if (i >= NN * 32) return;
  int v = i >> 5, o = i & 31;
  float acc = b[o];
#pragma unroll
  for (int c = 0; c < 64; c++) acc = fmaf(x[v * 64 + c], W[c * 32 + o], acc);
  out[i] = acc;
}

extern "C" void kernel_launch(void* const* d_in, const int* in_sizes, int n_in,
                              void* d_out, int out_size, void* d_ws, size_t ws_size,
                              hipStream_t stream) {
  const float* x = (const float*)d_in[0];
  const int* e0 = (const int*)d_in[1];
  const int* e1 = (const int*)d_in[2];
  const int* e2 = (const int*)d_in[3];
  const int* e3 = (const int*)d_in[4];
  const float* W0 = (const float*)d_in[5];
  const float* as0 = (const float*)d_in[6];
  const float* ad0 = (const float*)d_in[7];
  const float* b0 = (const float*)d_in[8];
  const float* W1 = (const float*)d_in[9];
  const float* as1 = (const float*)d_in[10];
  const float* ad1 = (const float*)d_in[11];
  const float* b1 = (const float*)d_in[12];
  const float* linW = (const float*)d_in[13];
  const float* linb = (const float*)d_in[14];
  float* out = (float*)d_out;
  (void)in_sizes; (void)n_in; (void)out_size;

  bool bigws = ws_size >= (size_t)185 * 1024 * 1024;

  char* wsb = (char*)d_ws;
  size_t off = 0;
  auto carve = [&](size_t bytes) -> char* {
    off = (off + 255) & ~(size_t)255;
    char* p = wsb + off;
    off += bytes;
    return p;
  };
  int* cnt     = (int*)carve((size_t)4 * NN * sizeof(int));
  int* tmp     = (int*)carve((size_t)4 * NN * sizeof(int));
  int* rp      = (int*)carve((size_t)4 * RP_STRIDE * sizeof(int));
  int* col     = (int*)carve((size_t)4 * EPN * sizeof(int));
  float* asrc  = (float*)carve((size_t)NN * 16 * sizeof(float));
  float* adst  = (float*)carve((size_t)NN * 16 * sizeof(float));
  float* PT0   = (float*)carve((size_t)32 * 128 * sizeof(float));
  float* PT1   = (float*)carve((size_t)32 * 64 * sizeof(float));
  float* bmean = (float*)carve((size_t)128 * sizeof(float));
  float* xmid  = (float*)carve((size_t)NN * 64 * sizeof(float));
  float* y     = (float*)carve((size_t)NN * (bigws ? 2048 : 512) * sizeof(float));
  float* zsep  = bigws ? nullptr : (float*)carve((size_t)4 * NN * 64 * sizeof(float));

  // CSR build
  hipMemsetAsync(cnt, 0, (size_t)4 * NN * sizeof(int), stream);
  k_count<<<(4 * NE + 255) / 256, 256, 0, stream>>>(e0 + NE, e1 + NE, e2 + NE, e3 + NE, cnt);
  k_scan<<<4, 256, 0, stream>>>(cnt, rp, tmp);
  k_fill<<<(4 * EPN + 255) / 256, 256, 0, stream>>>(e0, e1, e2, e3, tmp, col);

  k_prep<<<25, 256, 0, stream>>>(W0, as0, ad0, b0, W1, as1, ad1, b1, PT0, PT1, bmean);

  if (bigws) {
    // ---- layer 0 (K=128, KT=2048) ----
    k_coef<128><<<5000, 256, 0, stream>>>(x, PT0, asrc, adst);
    for (int t = 0; t < 4; t++)
      k_aggx2<128><<<5000, 256, 0, stream>>>(rp + t * RP_STRIDE, col + (size_t)t * EPN,
                                             asrc + t * 4, adst + t * 4, x,
                                             y + t * 512, 2048);
    k_out_m<128><<<313, 256, 0, stream>>>(y, W0, bmean, xmid);
    // ---- layer 1 (K=64, KT=1024) ----
    k_coef<64><<<5000, 256, 0, stream>>>(xmid, PT1, asrc, adst);
    for (int t = 0; t < 4; t++)
      k_aggx2<64><<<5000, 256, 0, stream>>>(rp + t * RP_STRIDE, col + (size_t)t * EPN,
                                            asrc + t * 4, adst + t * 4, xmid,
                                            y + t * 256, 1024);
    k_out_m<64><<<313, 256, 0, stream>>>(y, W1, bmean + 64, xmid);
  } else {
    // ---- layer 0 ----
    k_coef<128><<<5000, 256, 0, stream>>>(x, PT0, asrc, adst);
    for (int t = 0; t < 4; t++) {
      k_aggx2<128><<<5000, 256, 0, stream>>>(rp + t * RP_STRIDE, col + (size_t)t * EPN,
                                             asrc + t * 4, adst + t * 4, x, y, 512);
      k_out<128><<<313, 256, 0, stream>>>(y, W0 + (size_t)t * 128 * 256,
                                          zsep + (size_t)t * NN * 64);
    }
    k_fin<<<(NN * 64 + 255) / 256, 256, 0, stream>>>(zsep, bmean, xmid);
    // ---- layer 1 ----
    k_coef<64><<<5000, 256, 0, stream>>>(xmid, PT1, asrc, adst);
    for (int t = 0; t < 4; t++) {
      k_aggx2<64><<<5000, 256, 0, stream>>>(rp + t * RP_STRIDE, col + (size_t)t * EPN,
                                            asrc + t * 4, adst + t * 4, xmid, y, 256);
      k_out<64><<<313, 256, 0, stream>>>(y, W1 + (size_t)t * 64 * 256,
                                         zsep + (size_t)t * NN * 64);
    }
    k_fin<<<(NN * 64 + 255) / 256, 256, 0, stream>>>(zsep, bmean + 64, xmid);
  }

  k_linear<<<(NN * 32 + 255) / 256, 256, 0, stream>>>(xmid, linW, linb, out);
}

// Round 9
// 520.294 us; speedup vs baseline: 1.6249x; 1.3117x over previous
//
#include <hip/hip_runtime.h>

#define NN 20000
#define NE 320000
#define EPN (NE + NN)   // edges + self loops = 340000
#define RP_STRIDE 20004
#define DCAP 96
#define KSPLIT 8

// ---------------- CSR build ----------------
__global__ void k_count(const int* __restrict__ d0, const int* __restrict__ d1,
                        const int* __restrict__ d2, const int* __restrict__ d3,
                        int* __restrict__ cnt) {
  int i = blockIdx.x * blockDim.x + threadIdx.x;
  if (i >= 4 * NE) return;
  int t = i / NE, e = i - t * NE;
  const int* d = t == 0 ? d0 : t == 1 ? d1 : t == 2 ? d2 : d3;
  atomicAdd(&cnt[t * NN + d[e]], 1);
}

// self-loop (+1 per node) folded into the scan
__global__ void k_scan(const int* __restrict__ cnt, int* __restrict__ rp, int* __restrict__ tmp) {
  int t = blockIdx.x;
  const int* c = cnt + t * NN;
  int* r = rp + t * RP_STRIDE;
  int* tm = tmp + t * NN;
  __shared__ int part[256];
  int tid = threadIdx.x;
  const int CH = (NN + 255) / 256;
  int lo = tid * CH, hi = min(lo + CH, NN);
  int s = 0;
  for (int i = lo; i < hi; i++) s += c[i] + 1;
  part[tid] = s;
  __syncthreads();
  if (tid == 0) {
    int run = 0;
    for (int i = 0; i < 256; i++) { int v = part[i]; part[i] = run; run += v; }
  }
  __syncthreads();
  int run = part[tid];
  for (int i = lo; i < hi; i++) { r[i] = run; tm[i] = run; run += c[i] + 1; }
  if (lo < NN && hi == NN) r[NN] = run;
}

__global__ void k_fill(const int* __restrict__ e0, const int* __restrict__ e1,
                       const int* __restrict__ e2, const int* __restrict__ e3,
                       int* __restrict__ tmp, int* __restrict__ col) {
  int i = blockIdx.x * blockDim.x + threadIdx.x;
  if (i >= 4 * EPN) return;
  int t = i / EPN, j = i - t * EPN;
  const int* eb = t == 0 ? e0 : t == 1 ? e1 : t == 2 ? e2 : e3;
  int s, d;
  if (j < NE) { s = eb[j]; d = eb[NE + j]; } else { s = d = j - NE; }
  int pos = atomicAdd(&tmp[t * NN + d], 1);
  col[(size_t)t * EPN + pos] = s;
}

// ---------------- prep: PT[slot][k] = sum_c W[t][k][h*64+c]*a[t][h][c]; bmean ----
__global__ void k_prep(const float* __restrict__ W0, const float* __restrict__ as0,
                       const float* __restrict__ ad0, const float* __restrict__ b0,
                       const float* __restrict__ W1, const float* __restrict__ as1,
                       const float* __restrict__ ad1, const float* __restrict__ b1,
                       float* __restrict__ PT0, float* __restrict__ PT1,
                       float* __restrict__ bmean) {
  int i = blockIdx.x * blockDim.x + threadIdx.x;
  if (i < 4096) {
    int r = i >> 7, k = i & 127;
    int sd = r >> 4, t = (r >> 2) & 3, h = r & 3;
    const float* a = (sd ? ad0 : as0) + (t * 4 + h) * 64;
    const float* wr = W0 + ((size_t)t * 128 + k) * 256 + h * 64;
    float s = 0.f;
    for (int c = 0; c < 64; c++) s = fmaf(wr[c], a[c], s);
    PT0[r * 128 + k] = s;
  } else if (i < 6144) {
    int j = i - 4096;
    int r = j >> 6, k = j & 63;
    int sd = r >> 4, t = (r >> 2) & 3, h = r & 3;
    const float* a = (sd ? ad1 : as1) + (t * 4 + h) * 64;
    const float* wr = W1 + ((size_t)t * 64 + k) * 256 + h * 64;
    float s = 0.f;
    for (int c = 0; c < 64; c++) s = fmaf(wr[c], a[c], s);
    PT1[r * 64 + k] = s;
  } else if (i < 6272) {
    int j = i - 6144;
    int l = j >> 6, c = j & 63;
    const float* b = l ? b1 : b0;
    bmean[j] = 0.25f * (b[c] + b[64 + c] + b[128 + c] + b[192 + c]);
  }
}

// ---------------- coefficients: asrc/adst[v][16] = x[v] @ PT^T ----------------
template <int K>
__global__ __launch_bounds__(256) void k_coef(const float* __restrict__ xin,
                                              const float* __restrict__ PT,
                                              float* __restrict__ asrc,
                                              float* __restrict__ adst) {
  __shared__ float PTs[32][K + 4];
  __shared__ float Xs[4][K];
  int tid = threadIdx.x;
#pragma unroll
  for (int j = 0; j < (32 * K) / 1024; j++) {
    int f4 = tid + j * 256;
    int r = f4 / (K / 4), c4 = (f4 % (K / 4)) * 4;
    *(float4*)&PTs[r][c4] = *(const float4*)(PT + r * K + c4);
  }
  int w = tid >> 6, lane = tid & 63;
  int v = blockIdx.x * 4 + w;
  if (lane * 2 < K)
    *(float2*)&Xs[w][lane * 2] = *(const float2*)(xin + (size_t)v * K + lane * 2);
  __syncthreads();
  int s = lane & 31, h2 = lane >> 5;
  float acc = 0.f;
#pragma unroll
  for (int i = 0; i < K / 8; i++) {
    int k = h2 * (K / 2) + i * 4;
    float4 p = *(const float4*)&PTs[s][k];
    float4 xv = *(const float4*)&Xs[w][k];
    acc = fmaf(p.x, xv.x, fmaf(p.y, xv.y, fmaf(p.z, xv.z, fmaf(p.w, xv.w, acc))));
  }
  acc += __shfl_xor(acc, 32);
  if (lane < 16) asrc[(size_t)v * 16 + lane] = acc;
  else if (lane < 32) adst[(size_t)v * 16 + (lane - 16)] = acc;
}

// ------- x-space aggregation v3: block = 1 node, wave = 1 edge type ----------
// Pass1: edge-per-lane, asrc gathered once, e->LDS, fmax tree; exp LDS-local.
// Pass2: pure gather. y[v][t*4K + h*K + k].
template <int K>
__global__ __launch_bounds__(256) void k_aggx3(
    const int* __restrict__ rp, const int* __restrict__ col,
    const float* __restrict__ asrc, const float* __restrict__ adst,
    const float* __restrict__ x, float* __restrict__ y) {
  constexpr int GL = K / 4;    // lanes per group (32 / 16)
  constexpr int G = 64 / GL;   // edge groups per wave (2 / 4)
  __shared__ float wl[4][DCAP * 4];
  __shared__ int scol[4][DCAP];
  int t = threadIdx.x >> 6, lane = threadIdx.x & 63;
  int v = blockIdx.x;
  int beg = rp[t * RP_STRIDE + v], deg = rp[t * RP_STRIDE + v + 1] - beg;
  const int* colt = col + (size_t)t * EPN + beg;
  float4 adv = *(const float4*)(adst + (size_t)v * 16 + t * 4);
  int g = lane / GL, c4 = (lane % GL) * 4;
  float acc[4][4] = {};
  float rz[4];

  if (deg <= DCAP) {
    float m0 = -1e30f, m1 = -1e30f, m2 = -1e30f, m3 = -1e30f;
    for (int i = lane; i < deg; i += 64) {
      int s = colt[i];
      scol[t][i] = s;
      float4 a = *(const float4*)(asrc + (size_t)s * 16 + t * 4);
      float e0 = a.x + adv.x; e0 = e0 > 0.f ? e0 : 0.2f * e0;
      float e1 = a.y + adv.y; e1 = e1 > 0.f ? e1 : 0.2f * e1;
      float e2 = a.z + adv.z; e2 = e2 > 0.f ? e2 : 0.2f * e2;
      float e3 = a.w + adv.w; e3 = e3 > 0.f ? e3 : 0.2f * e3;
      *(float4*)&wl[t][i * 4] = make_float4(e0, e1, e2, e3);
      m0 = fmaxf(m0, e0); m1 = fmaxf(m1, e1);
      m2 = fmaxf(m2, e2); m3 = fmaxf(m3, e3);
    }
#pragma unroll
    for (int st = 1; st < 64; st <<= 1) {
      m0 = fmaxf(m0, __shfl_xor(m0, st)); m1 = fmaxf(m1, __shfl_xor(m1, st));
      m2 = fmaxf(m2, __shfl_xor(m2, st)); m3 = fmaxf(m3, __shfl_xor(m3, st));
    }
    float z0 = 0.f, z1 = 0.f, z2 = 0.f, z3 = 0.f;
    for (int i = lane; i < deg; i += 64) {
      float4 e = *(const float4*)&wl[t][i * 4];
      e.x = __expf(e.x - m0); e.y = __expf(e.y - m1);
      e.z = __expf(e.z - m2); e.w = __expf(e.w - m3);
      *(float4*)&wl[t][i * 4] = e;
      z0 += e.x; z1 += e.y; z2 += e.z; z3 += e.w;
    }
#pragma unroll
    for (int st = 1; st < 64; st <<= 1) {
      z0 += __shfl_xor(z0, st); z1 += __shfl_xor(z1, st);
      z2 += __shfl_xor(z2, st); z3 += __shfl_xor(z3, st);
    }
    rz[0] = 1.f / z0; rz[1] = 1.f / z1; rz[2] = 1.f / z2; rz[3] = 1.f / z3;
    for (int i = g; i < deg; i += G) {
      float4 wv = *(const float4*)&wl[t][i * 4];
      float4 xv = *(const float4*)(x + (size_t)scol[t][i] * K + c4);
      acc[0][0] = fmaf(wv.x, xv.x, acc[0][0]); acc[0][1] = fmaf(wv.x, xv.y, acc[0][1]);
      acc[0][2] = fmaf(wv.x, xv.z, acc[0][2]); acc[0][3] = fmaf(wv.x, xv.w, acc[0][3]);
      acc[1][0] = fmaf(wv.y, xv.x, acc[1][0]); acc[1][1] = fmaf(wv.y, xv.y, acc[1][1]);
      acc[1][2] = fmaf(wv.y, xv.z, acc[1][2]); acc[1][3] = fmaf(wv.y, xv.w, acc[1][3]);
      acc[2][0] = fmaf(wv.z, xv.x, acc[2][0]); acc[2][1] = fmaf(wv.z, xv.y, acc[2][1]);
      acc[2][2] = fmaf(wv.z, xv.z, acc[2][2]); acc[2][3] = fmaf(wv.z, xv.w, acc[2][3]);
      acc[3][0] = fmaf(wv.w, xv.x, acc[3][0]); acc[3][1] = fmaf(wv.w, xv.y, acc[3][1]);
      acc[3][2] = fmaf(wv.w, xv.z, acc[3][2]); acc[3][3] = fmaf(wv.w, xv.w, acc[3][3]);
    }
  } else {
    // fallback: online softmax (deg unbounded)
    float m[4] = {-1e30f, -1e30f, -1e30f, -1e30f};
    float z[4] = {0.f, 0.f, 0.f, 0.f};
    float advv[4] = {adv.x, adv.y, adv.z, adv.w};
    for (int i = g; i < deg; i += G) {
      int s = colt[i];
      float4 a = *(const float4*)(asrc + (size_t)s * 16 + t * 4);
      float av[4] = {a.x, a.y, a.z, a.w};
#pragma unroll
      for (int h = 0; h < 4; h++) {
        float e = av[h] + advv[h];
        e = e > 0.f ? e : 0.2f * e;
        float nm = fmaxf(m[h], e);
        z[h] = z[h] * __expf(m[h] - nm) + __expf(e - nm);
        m[h] = nm;
      }
    }
#pragma unroll
    for (int st = GL; st < 64; st <<= 1)
#pragma unroll
      for (int h = 0; h < 4; h++) {
        float m2_ = __shfl_xor(m[h], st);
        float z2_ = __shfl_xor(z[h], st);
        float nm = fmaxf(m[h], m2_);
        z[h] = z[h] * __expf(m[h] - nm) + z2_ * __expf(m2_ - nm);
        m[h] = nm;
      }
#pragma unroll
    for (int h = 0; h < 4; h++) rz[h] = 1.f / z[h];
    for (int i = g; i < deg; i += G) {
      int s = colt[i];
      float4 a = *(const float4*)(asrc + (size_t)s * 16 + t * 4);
      float4 xv = *(const float4*)(x + (size_t)s * K + c4);
      float av[4] = {a.x, a.y, a.z, a.w};
#pragma unroll
      for (int h = 0; h < 4; h++) {
        float e = av[h] + advv[h];
        e = e > 0.f ? e : 0.2f * e;
        float ww = __expf(e - m[h]);
        acc[h][0] = fmaf(ww, xv.x, acc[h][0]);
        acc[h][1] = fmaf(ww, xv.y, acc[h][1]);
        acc[h][2] = fmaf(ww, xv.z, acc[h][2]);
        acc[h][3] = fmaf(ww, xv.w, acc[h][3]);
      }
    }
  }
#pragma unroll
  for (int st = GL; st < 64; st <<= 1)
#pragma unroll
    for (int h = 0; h < 4; h++) {
      acc[h][0] += __shfl_xor(acc[h][0], st);
      acc[h][1] += __shfl_xor(acc[h][1], st);
      acc[h][2] += __shfl_xor(acc[h][2], st);
      acc[h][3] += __shfl_xor(acc[h][3], st);
    }
  if (lane < GL) {
#pragma unroll
    for (int h = 0; h < 4; h++)
      *(float4*)(y + (size_t)v * (16 * K) + (t * 4 + h) * K + c4) =
          make_float4(acc[h][0] * rz[h], acc[h][1] * rz[h],
                      acc[h][2] * rz[h], acc[h][3] * rz[h]);
  }
}

// ------- split-K output GEMM: part[ks] = y[:, chunk] @ B[chunk, :] -------
template <int K>
__global__ __launch_bounds__(256) void k_out_s(const float* __restrict__ y,
                                               const float* __restrict__ W,
                                               float* __restrict__ part) {
  constexpr int KT = 16 * K;
  constexpr int CHUNK = KT / KSPLIT;
  __shared__ float As[32][65];
  __shared__ float Bs[32][68];
  int tid = threadIdx.x;
  int row0 = blockIdx.x * 64;
  int ks = blockIdx.y;
  int tx = tid & 15, ty = tid >> 4;
  float acc[4][4] = {};
  for (int kb = ks * CHUNK; kb < (ks + 1) * CHUNK; kb += 32) {
    int tt = kb / (4 * K), hh = (kb / K) & 3, kk0 = kb % K;
#pragma unroll
    for (int j = 0; j < 2; j++) {
      int idx = tid + j * 256;
      int r = idx >> 3, k4 = (idx & 7) * 4;
      float4 vv = make_float4(0.f, 0.f, 0.f, 0.f);
      if (row0 + r < NN) vv = *(const float4*)(y + (size_t)(row0 + r) * KT + kb + k4);
      As[k4 + 0][r] = vv.x; As[k4 + 1][r] = vv.y;
      As[k4 + 2][r] = vv.z; As[k4 + 3][r] = vv.w;
    }
#pragma unroll
    for (int j = 0; j < 2; j++) {
      int idx = tid + j * 256;
      int kk = idx >> 4, cc4 = (idx & 15) * 4;
      *(float4*)&Bs[kk][cc4] =
          *(const float4*)(W + ((size_t)tt * K + kk0 + kk) * 256 + hh * 64 + cc4);
    }
    __syncthreads();
#pragma unroll 4
    for (int kk = 0; kk < 32; kk++) {
      float4 a4 = *(const float4*)&As[kk][ty * 4];
      float4 b4 = *(const float4*)&Bs[kk][tx * 4];
      float aa[4] = {a4.x, a4.y, a4.z, a4.w};
      float bb[4] = {b4.x, b4.y, b4.z, b4.w};
#pragma unroll
      for (int i = 0; i < 4; i++)
#pragma unroll
        for (int j = 0; j < 4; j++) acc[i][j] = fmaf(aa[i], bb[j], acc[i][j]);
    }
    __syncthreads();
  }
#pragma unroll
  for (int i = 0; i < 4; i++) {
    int gr = row0 + ty * 4 + i;
    if (gr < NN)
      *(float4*)(part + (size_t)ks * NN * 64 + (size_t)gr * 64 + tx * 4) =
          make_float4(acc[i][0], acc[i][1], acc[i][2], acc[i][3]);
  }
}

// reduce KSPLIT partials: xout = relu(1/16*sum + bmean)
__global__ void k_red(const float* __restrict__ part, const float* __restrict__ bm,
                      float* __restrict__ xout) {
  int i = blockIdx.x * blockDim.x + threadIdx.x;   // float4 index
  if (i >= NN * 16) return;
  float4 s = make_float4(0.f, 0.f, 0.f, 0.f);
#pragma unroll
  for (int ks = 0; ks < KSPLIT; ks++) {
    float4 p = *(const float4*)(part + (size_t)ks * NN * 64 + (size_t)i * 4);
    s.x += p.x; s.y += p.y; s.z += p.z; s.w += p.w;
  }
  float4 b = *(const float4*)(bm + ((i & 15) << 2));
  float4 o;
  o.x = fmaxf(0.0625f * s.x + b.x, 0.f);
  o.y = fmaxf(0.0625f * s.y + b.y, 0.f);
  o.z = fmaxf(0.0625f * s.z + b.z, 0.f);
  o.w = fmaxf(0.0625f * s.w + b.w, 0.f);
  *(float4*)(xout + (size_t)i * 4) = o;
}

// ------- merged (non-split) output GEMM, fallback for smaller ws -------
template <int K>
__global__ __launch_bounds__(256) void k_out_m(const float* __restrict__ y,
                                               const float* __restrict__ W,
                                               const float* __restrict__ bm,
                                               float* __restrict__ xout) {
  constexpr int KT = 16 * K;
  __shared__ float As[32][65];
  __shared__ float Bs[32][68];
  int tid = threadIdx.x;
  int row0 = blockIdx.x * 64;
  int tx = tid & 15, ty = tid >> 4;
  float acc[4][4] = {};
  for (int kb = 0; kb < KT; kb += 32) {
    int tt = kb / (4 * K), hh = (kb / K) & 3, kk0 = kb % K;
#pragma unroll
    for (int j = 0; j < 2; j++) {
      int idx = tid + j * 256;
      int r = idx >> 3, k4 = (idx & 7) * 4;
      float4 vv = make_float4(0.f, 0.f, 0.f, 0.f);
      if (row0 + r < NN) vv = *(const float4*)(y + (size_t)(row0 + r) * KT + kb + k4);
      As[k4 + 0][r] = vv.x; As[k4 + 1][r] = vv.y;
      As[k4 + 2][r] = vv.z; As[k4 + 3][r] = vv.w;
    }
#pragma unroll
    for (int j = 0; j < 2; j++) {
      int idx = tid + j * 256;
      int kk = idx >> 4, cc4 = (idx & 15) * 4;
      *(float4*)&Bs[kk][cc4] =
          *(const float4*)(W + ((size_t)tt * K + kk0 + kk) * 256 + hh * 64 + cc4);
    }
    __syncthreads();
#pragma unroll 4
    for (int kk = 0; kk < 32; kk++) {
      float4 a4 = *(const float4*)&As[kk][ty * 4];
      float4 b4 = *(const float4*)&Bs[kk][tx * 4];
      float aa[4] = {a4.x, a4.y, a4.z, a4.w};
      float bb[4] = {b4.x, b4.y, b4.z, b4.w};
#pragma unroll
      for (int i = 0; i < 4; i++)
#pragma unroll
        for (int j = 0; j < 4; j++) acc[i][j] = fmaf(aa[i], bb[j], acc[i][j]);
    }
    __syncthreads();
  }
#pragma unroll
  for (int i = 0; i < 4; i++) {
    int gr = row0 + ty * 4 + i;
    if (gr < NN) {
      float4 o;
      o.x = fmaxf(0.0625f * acc[i][0] + bm[tx * 4 + 0], 0.f);
      o.y = fmaxf(0.0625f * acc[i][1] + bm[tx * 4 + 1], 0.f);
      o.z = fmaxf(0.0625f * acc[i][2] + bm[tx * 4 + 2], 0.f);
      o.w = fmaxf(0.0625f * acc[i][3] + bm[tx * 4 + 3], 0.f);
      *(float4*)(xout + (size_t)gr * 64 + tx * 4) = o;
    }
  }
}

__global__ void k_linear(const float* __restrict__ x, const float* __restrict__ W,
                         const float* __restrict__ b, float* __restrict__ out) {
  int i = blockIdx.x * blockDim.x + threadIdx.x;
  if (i >= NN * 32) return;
  int v = i >> 5, o = i & 31;
  float acc = b[o];
#pragma unroll
  for (int c = 0; c < 64; c++) acc = fmaf(x[v * 64 + c], W[c * 32 + o], acc);
  out[i] = acc;
}

extern "C" void kernel_launch(void* const* d_in, const int* in_sizes, int n_in,
                              void* d_out, int out_size, void* d_ws, size_t ws_size,
                              hipStream_t stream) {
  const float* x = (const float*)d_in[0];
  const int* e0 = (const int*)d_in[1];
  const int* e1 = (const int*)d_in[2];
  const int* e2 = (const int*)d_in[3];
  const int* e3 = (const int*)d_in[4];
  const float* W0 = (const float*)d_in[5];
  const float* as0 = (const float*)d_in[6];
  const float* ad0 = (const float*)d_in[7];
  const float* b0 = (const float*)d_in[8];
  const float* W1 = (const float*)d_in[9];
  const float* as1 = (const float*)d_in[10];
  const float* ad1 = (const float*)d_in[11];
  const float* b1 = (const float*)d_in[12];
  const float* linW = (const float*)d_in[13];
  const float* linb = (const float*)d_in[14];
  float* out = (float*)d_out;
  (void)in_sizes; (void)n_in; (void)out_size;

  bool splitk = ws_size >= (size_t)230 * 1024 * 1024;

  char* wsb = (char*)d_ws;
  size_t off = 0;
  auto carve = [&](size_t bytes) -> char* {
    off = (off + 255) & ~(size_t)255;
    char* p = wsb + off;
    off += bytes;
    return p;
  };
  int* cnt     = (int*)carve((size_t)4 * NN * sizeof(int));
  int* tmp     = (int*)carve((size_t)4 * NN * sizeof(int));
  int* rp      = (int*)carve((size_t)4 * RP_STRIDE * sizeof(int));
  int* col     = (int*)carve((size_t)4 * EPN * sizeof(int));
  float* asrc  = (float*)carve((size_t)NN * 16 * sizeof(float));
  float* adst  = (float*)carve((size_t)NN * 16 * sizeof(float));
  float* PT0   = (float*)carve((size_t)32 * 128 * sizeof(float));
  float* PT1   = (float*)carve((size_t)32 * 64 * sizeof(float));
  float* bmean = (float*)carve((size_t)128 * sizeof(float));
  float* xmid  = (float*)carve((size_t)NN * 64 * sizeof(float));
  float* y     = (float*)carve((size_t)NN * 2048 * sizeof(float));
  float* part  = splitk ? (float*)carve((size_t)KSPLIT * NN * 64 * sizeof(float)) : nullptr;

  // CSR build
  hipMemsetAsync(cnt, 0, (size_t)4 * NN * sizeof(int), stream);
  k_count<<<(4 * NE + 255) / 256, 256, 0, stream>>>(e0 + NE, e1 + NE, e2 + NE, e3 + NE, cnt);
  k_scan<<<4, 256, 0, stream>>>(cnt, rp, tmp);
  k_fill<<<(4 * EPN + 255) / 256, 256, 0, stream>>>(e0, e1, e2, e3, tmp, col);

  k_prep<<<25, 256, 0, stream>>>(W0, as0, ad0, b0, W1, as1, ad1, b1, PT0, PT1, bmean);

  // ---- layer 0 (K=128, KT=2048) ----
  k_coef<128><<<5000, 256, 0, stream>>>(x, PT0, asrc, adst);
  k_aggx3<128><<<NN, 256, 0, stream>>>(rp, col, asrc, adst, x, y);
  if (splitk) {
    k_out_s<128><<<dim3(313, KSPLIT), 256, 0, stream>>>(y, W0, part);
    k_red<<<(NN * 16 + 255) / 256, 256, 0, stream>>>(part, bmean, xmid);
  } else {
    k_out_m<128><<<313, 256, 0, stream>>>(y, W0, bmean, xmid);
  }

  // ---- layer 1 (K=64, KT=1024) ----
  k_coef<64><<<5000, 256, 0, stream>>>(xmid, PT1, asrc, adst);
  k_aggx3<64><<<NN, 256, 0, stream>>>(rp, col, asrc, adst, xmid, y);
  if (splitk) {
    k_out_s<64><<<dim3(313, KSPLIT), 256, 0, stream>>>(y, W1, part);
    k_red<<<(NN * 16 + 255) / 256, 256, 0, stream>>>(part, bmean + 64, xmid);
  } else {
    k_out_m<64><<<313, 256, 0, stream>>>(y, W1, bmean + 64, xmid);
  }

  k_linear<<<(NN * 32 + 255) / 256, 256, 0, stream>>>(xmid, linW, linb, out);
}